// Round 14
// baseline (190.621 us; speedup 1.0000x reference)
//
#include <hip/hip_runtime.h>
#include <hip/hip_bf16.h>

// Problem constants
constexpr int BB = 2;        // batch
constexpr int CC = 128;      // channels
constexpr int LL = 4096;     // H*W sequence length
constexpr int DI = 256;      // d_inner
constexpr int DS = 16;       // d_state
constexpr int DR = 8;        // dt_rank
constexpr int DX = 40;       // dt_rank + 2*d_state
constexpr int NZ = 2 * BB;   // branches * batch
constexpr int CH = 8;        // scan chunk length (per thread)
constexpr int NCH = LL / CH; // 512 chunks == threads per scan WG
constexpr int SEG = 32;      // phase2 segments (16 chunks each)

typedef short bf16x8 __attribute__((ext_vector_type(8)));
typedef float f32x4 __attribute__((ext_vector_type(4)));

__device__ __forceinline__ unsigned short f2bf(float x) {
    __hip_bfloat16 h = __float2bfloat16(x);
    return *(unsigned short*)&h;
}
__device__ __forceinline__ float fast_rcp(float x) { return __builtin_amdgcn_rcpf(x); }
__device__ __forceinline__ float siluf(float x) { return x * fast_rcp(1.f + __expf(-x)); }
__device__ __forceinline__ float softplusf(float x) {
    const float z = exp2f(x * 1.44269504f);
    return (x > 20.f) ? x : 0.69314718f * log2f(1.f + z);
}

// ---------------- Weight fp32 -> bf16 conversion (once per call) -------------
__global__ __launch_bounds__(256) void convert_w_kernel(
    const float* __restrict__ Winp, const float* __restrict__ Winm,
    const float* __restrict__ Wzp, const float* __restrict__ Wzm,
    const float* __restrict__ Woutp, const float* __restrict__ Woutm,
    const float* __restrict__ Wxp, const float* __restrict__ Wxm,
    unsigned short* __restrict__ dst)
{
    const int i = blockIdx.x * 256 + threadIdx.x;
    const float* src; int off;
    if (i < 32768)       { src = Winp;  off = i; }
    else if (i < 65536)  { src = Winm;  off = i - 32768; }
    else if (i < 98304)  { src = Wzp;   off = i - 65536; }
    else if (i < 131072) { src = Wzm;   off = i - 98304; }
    else if (i < 163840) { src = Woutp; off = i - 131072; }
    else if (i < 196608) { src = Woutm; off = i - 163840; }
    else if (i < 206848) { src = Wxp;   off = i - 196608; }
    else                 { src = Wxm;   off = i - 206848; }
    dst[i] = f2bf(src[off]);
}

// ---------------- LayerNorm over C -> bf16 x3, (zi, C, L) layout -------------
__global__ __launch_bounds__(256) void layernorm_kernel(
    const float* __restrict__ pan, const float* __restrict__ ms,
    const float* __restrict__ wpan, const float* __restrict__ bpan,
    const float* __restrict__ wms, const float* __restrict__ bms,
    unsigned short* __restrict__ x3b)
{
    const int zi = blockIdx.y;
    const int br = zi >> 1, b = zi & 1;
    const float* inp = br ? ms : pan;
    const float* wp = br ? wms : wpan;
    const float* bp = br ? bms : bpan;
    const int l0 = blockIdx.x * 64;
    const int t = threadIdx.x;
    const int lo = t & 63, c4 = t >> 6;
    const float* base = inp + (size_t)b * CC * LL + l0 + lo;
    float vals[32];
    float s = 0.f, s2 = 0.f;
    #pragma unroll
    for (int i = 0; i < 32; i++) {
        const int c = c4 * 32 + i;
        const float v = base[(size_t)c * LL];
        vals[i] = v; s += v; s2 += v * v;
    }
    __shared__ float red[2][4][64];
    red[0][c4][lo] = s; red[1][c4][lo] = s2;
    __syncthreads();
    const float S  = red[0][0][lo] + red[0][1][lo] + red[0][2][lo] + red[0][3][lo];
    const float S2 = red[1][0][lo] + red[1][1][lo] + red[1][2][lo] + red[1][3][lo];
    const float mu = S * (1.f / CC);
    const float var = S2 * (1.f / CC) - mu * mu;
    const float rstd = rsqrtf(var + 1e-5f);
    unsigned short* out = x3b + (size_t)zi * CC * LL + l0 + lo;
    #pragma unroll
    for (int i = 0; i < 32; i++) {
        const int c = c4 * 32 + i;
        out[(size_t)c * LL] = f2bf((vals[i] - mu) * rstd * wp[c] + bp[c]);
    }
}

// ================= MFMA bf16 GEMMs =================
__global__ __launch_bounds__(256) void gemm_inz_mfma(
    const unsigned short* __restrict__ wb, const unsigned short* __restrict__ x3b,
    float* __restrict__ xpre, float* __restrict__ zy)
{
    const int zi = blockIdx.z;
    const int my = blockIdx.y;
    const unsigned short* W = wb + (my >= 4 ? 65536 : 0) + (zi >= BB ? 32768 : 0);
    float* outp = (my >= 4) ? zy : xpre;
    const int mbase = (my & 3) * 64;
    const unsigned short* Xb = x3b + (size_t)zi * CC * LL;
    const int n0 = blockIdx.x * 64;
    const int t = threadIdx.x;
    const int w = t >> 6, ln = t & 63;
    const int nf = ln & 15, qb = ln >> 4;
    bf16x8 afrag[4];
    const int mrow = mbase + w * 16 + nf;
    #pragma unroll
    for (int c = 0; c < 4; c++)
        afrag[c] = *(const bf16x8*)(W + (size_t)mrow * CC + c * 32 + qb * 8);
    __shared__ unsigned short Bs[64][40];
    unsigned* Bw = (unsigned*)Bs;
    f32x4 acc[4] = {};
    const int kp = t >> 4, n4 = (t & 15) * 4;
    #pragma unroll
    for (int kc = 0; kc < 4; kc++) {
        const ushort4 a0 = *(const ushort4*)(Xb + (size_t)(kc * 32 + 2 * kp) * LL + n0 + n4);
        const ushort4 a1 = *(const ushort4*)(Xb + (size_t)(kc * 32 + 2 * kp + 1) * LL + n0 + n4);
        if (kc) __syncthreads();
        Bw[(n4 + 0) * 20 + kp] = (unsigned)a0.x | ((unsigned)a1.x << 16);
        Bw[(n4 + 1) * 20 + kp] = (unsigned)a0.y | ((unsigned)a1.y << 16);
        Bw[(n4 + 2) * 20 + kp] = (unsigned)a0.z | ((unsigned)a1.z << 16);
        Bw[(n4 + 3) * 20 + kp] = (unsigned)a0.w | ((unsigned)a1.w << 16);
        __syncthreads();
        #pragma unroll
        for (int ns = 0; ns < 4; ns++) {
            const bf16x8 bf = *(const bf16x8*)(&Bs[ns * 16 + nf][qb * 8]);
            acc[ns] = __builtin_amdgcn_mfma_f32_16x16x32_bf16(afrag[kc], bf, acc[ns], 0, 0, 0);
        }
    }
    #pragma unroll
    for (int ns = 0; ns < 4; ns++)
        #pragma unroll
        for (int r = 0; r < 4; r++) {
            const int m = mbase + w * 16 + qb * 4 + r;
            outp[((size_t)zi * DI + m) * LL + n0 + ns * 16 + nf] = acc[ns][r];
        }
}

__global__ __launch_bounds__(256) void gemm_x_mfma(
    const unsigned short* __restrict__ wb, const float* __restrict__ xpre,
    const float* __restrict__ cw0, const float* __restrict__ cb0,
    const float* __restrict__ cw1, const float* __restrict__ cb1,
    float* __restrict__ xdbl)
{
    const int zi = blockIdx.z;
    const unsigned short* W = wb + 196608 + (zi >= BB ? 10240 : 0);
    const float* cw = (zi >= BB) ? cw1 : cw0;
    const float* cb = (zi >= BB) ? cb1 : cb0;
    const float* Xb = xpre + (size_t)zi * DI * LL;
    const int n0 = blockIdx.x * 64;
    const int t = threadIdx.x;
    const int w = t >> 6, ln = t & 63;
    const int nf = ln & 15, qb = ln >> 4;
    bf16x8 zfrag;
    #pragma unroll
    for (int j = 0; j < 8; j++) zfrag[j] = 0;
    bf16x8 afrag[8];
    const int mrow = w * 16 + nf;
    #pragma unroll
    for (int c = 0; c < 8; c++)
        afrag[c] = (mrow < DX) ? *(const bf16x8*)(W + (size_t)mrow * DI + c * 32 + qb * 8) : zfrag;
    __shared__ unsigned short Bs[64][40];
    unsigned* Bw = (unsigned*)Bs;
    f32x4 acc[4] = {};
    const int kp = t >> 4, n4 = (t & 15) * 4;
    #pragma unroll
    for (int kc = 0; kc < 8; kc++) {
        float vals[2][4];
        #pragma unroll
        for (int rr = 0; rr < 2; rr++) {
            const int e = kc * 32 + 2 * kp + rr;
            const float* xp = Xb + (size_t)e * LL + n0 + n4;
            const float4 cur = *(const float4*)xp;
            float xm1, xm2, xm3;
            if (n0 + n4 == 0) { xm1 = 0.f; xm2 = 0.f; xm3 = 0.f; }
            else { xm1 = xp[-1]; xm2 = xp[-2]; xm3 = xp[-3]; }
            const float w0 = cw[e * 4 + 0], w1 = cw[e * 4 + 1];
            const float w2 = cw[e * 4 + 2], w3 = cw[e * 4 + 3];
            const float bias = cb[e];
            vals[rr][0] = siluf(w0 * xm3 + w1 * xm2 + w2 * xm1 + w3 * cur.x + bias);
            vals[rr][1] = siluf(w0 * xm2 + w1 * xm1 + w2 * cur.x + w3 * cur.y + bias);
            vals[rr][2] = siluf(w0 * xm1 + w1 * cur.x + w2 * cur.y + w3 * cur.z + bias);
            vals[rr][3] = siluf(w0 * cur.x + w1 * cur.y + w2 * cur.z + w3 * cur.w + bias);
        }
        if (kc) __syncthreads();
        #pragma unroll
        for (int j = 0; j < 4; j++)
            Bw[(n4 + j) * 20 + kp] = (unsigned)f2bf(vals[0][j]) | ((unsigned)f2bf(vals[1][j]) << 16);
        __syncthreads();
        #pragma unroll
        for (int ns = 0; ns < 4; ns++) {
            const bf16x8 bf = *(const bf16x8*)(&Bs[ns * 16 + nf][qb * 8]);
            acc[ns] = __builtin_amdgcn_mfma_f32_16x16x32_bf16(afrag[kc], bf, acc[ns], 0, 0, 0);
        }
    }
    #pragma unroll
    for (int ns = 0; ns < 4; ns++)
        #pragma unroll
        for (int r = 0; r < 4; r++) {
            const int m = w * 16 + qb * 4 + r;
            if (m < DX)
                xdbl[((size_t)zi * DX + m) * LL + n0 + ns * 16 + nf] = acc[ns][r];
        }
}

__global__ __launch_bounds__(256) void gemm_out_mfma(
    const unsigned short* __restrict__ wb, const unsigned short* __restrict__ yb,
    float* __restrict__ outg)
{
    const int zi = blockIdx.z;
    const unsigned short* W = wb + 131072 + (zi >= BB ? 32768 : 0);
    const int mbase = blockIdx.y * 64;
    const unsigned short* Xb = yb + (size_t)zi * DI * LL;
    const int n0 = blockIdx.x * 64;
    const int t = threadIdx.x;
    const int w = t >> 6, ln = t & 63;
    const int nf = ln & 15, qb = ln >> 4;
    bf16x8 afrag[8];
    const int mrow = mbase + w * 16 + nf;
    #pragma unroll
    for (int c = 0; c < 8; c++)
        afrag[c] = *(const bf16x8*)(W + (size_t)mrow * DI + c * 32 + qb * 8);
    __shared__ unsigned short Bs[64][40];
    unsigned* Bw = (unsigned*)Bs;
    f32x4 acc[4] = {};
    const int kp = t >> 4, n4 = (t & 15) * 4;
    #pragma unroll
    for (int kc = 0; kc < 8; kc++) {
        const ushort4 a0 = *(const ushort4*)(Xb + (size_t)(kc * 32 + 2 * kp) * LL + n0 + n4);
        const ushort4 a1 = *(const ushort4*)(Xb + (size_t)(kc * 32 + 2 * kp + 1) * LL + n0 + n4);
        if (kc) __syncthreads();
        Bw[(n4 + 0) * 20 + kp] = (unsigned)a0.x | ((unsigned)a1.x << 16);
        Bw[(n4 + 1) * 20 + kp] = (unsigned)a0.y | ((unsigned)a1.y << 16);
        Bw[(n4 + 2) * 20 + kp] = (unsigned)a0.z | ((unsigned)a1.z << 16);
        Bw[(n4 + 3) * 20 + kp] = (unsigned)a0.w | ((unsigned)a1.w << 16);
        __syncthreads();
        #pragma unroll
        for (int ns = 0; ns < 4; ns++) {
            const bf16x8 bf = *(const bf16x8*)(&Bs[ns * 16 + nf][qb * 8]);
            acc[ns] = __builtin_amdgcn_mfma_f32_16x16x32_bf16(afrag[kc], bf, acc[ns], 0, 0, 0);
        }
    }
    #pragma unroll
    for (int ns = 0; ns < 4; ns++)
        #pragma unroll
        for (int r = 0; r < 4; r++) {
            const int m = mbase + w * 16 + qb * 4 + r;
            outg[((size_t)zi * CC + m) * LL + n0 + ns * 16 + nf] = acc[ns][r];
        }
}

// ================= Fully fused selective scan (512 thr, CH=8) ===============
// Register-diet build (round-13 showed VGPR=32 + 39 MB scratch spill traffic):
// main-body live set reduced to e/rdlx/pw/y (32 floats): rdl is recovered in
// the generic path via -ln(e); rx is folded into rdlx in the prolog and
// RECOMPUTED in the gate epilog from an L2-warm x reload.
__global__ __launch_bounds__(512, 8) void scan_fused(
    const float* __restrict__ xpre, const float* __restrict__ xdbl,
    const float* __restrict__ A_log,
    const float* __restrict__ Wdt0, const float* __restrict__ Wdt1,
    const float* __restrict__ bdt0, const float* __restrict__ bdt1,
    const float* __restrict__ cw0, const float* __restrict__ cb0,
    const float* __restrict__ cw1, const float* __restrict__ cb1,
    const float* __restrict__ D0, const float* __restrict__ D1,
    const float* __restrict__ zbuf, unsigned short* __restrict__ yb)
{
    const int blk = blockIdx.x;          // zi*DI + d
    const int zi = blk >> 8;
    const int d  = blk & (DI - 1);
    const int t = threadIdx.x;
    const int l0 = t * CH;
    __shared__ float Ssh[DS * (NCH + 1)];   // stride 513
    __shared__ float sdl_sh[NCH];
    __shared__ float Pseg[DS * (SEG + 1)];  // stride 33
    __shared__ float Sseg[DS * (SEG + 1)];
    const float* x_g = xpre + (size_t)blk * LL;
    const float* xdb = xdbl + (size_t)zi * DX * LL;
    const float* Wdt = (zi >= BB) ? Wdt1 : Wdt0;
    const float* bdt = (zi >= BB) ? bdt1 : bdt0;
    const float dbias = bdt[d];
    const float* cw = (zi >= BB) ? cw1 : cw0;
    const float* cb = (zi >= BB) ? cb1 : cb0;
    const float w0 = cw[d * 4 + 0], w1 = cw[d * 4 + 1];
    const float w2 = cw[d * 4 + 2], w3 = cw[d * 4 + 3];
    const float cbias = cb[d];
    float e[CH], rdlx[CH];
    {
        // ---- x + conv + SiLU (prolog-local rx) ----
        float rx[CH];
        {
            float xv[CH + 3];
            if (t > 0) {
                const float4 hm = *(const float4*)(x_g + l0 - 4);
                xv[0] = hm.y; xv[1] = hm.z; xv[2] = hm.w;
            } else { xv[0] = 0.f; xv[1] = 0.f; xv[2] = 0.f; }
            #pragma unroll
            for (int j = 0; j < 2; j++) {
                const float4 v = *(const float4*)(x_g + l0 + 4 * j);
                xv[4 * j + 3] = v.x; xv[4 * j + 4] = v.y;
                xv[4 * j + 5] = v.z; xv[4 * j + 6] = v.w;
            }
            #pragma unroll
            for (int i = 0; i < CH; i++)
                rx[i] = siluf(w0 * xv[i] + w1 * xv[i + 1] + w2 * xv[i + 2] + w3 * xv[i + 3] + cbias);
        }
        // ---- delta pre-activation (prolog-local acc) ----
        float acc[CH];
        #pragma unroll
        for (int i = 0; i < CH; i++) acc[i] = dbias;
        #pragma unroll
        for (int r = 0; r < DR; r++) {
            const float wr = Wdt[d * DR + r];
            const float* rp = xdb + (size_t)r * LL + l0;
            #pragma unroll
            for (int j = 0; j < 2; j++) {
                const float4 v = *(const float4*)(rp + 4 * j);
                acc[4 * j + 0] = fmaf(wr, v.x, acc[4 * j + 0]);
                acc[4 * j + 1] = fmaf(wr, v.y, acc[4 * j + 1]);
                acc[4 * j + 2] = fmaf(wr, v.z, acc[4 * j + 2]);
                acc[4 * j + 3] = fmaf(wr, v.w, acc[4 * j + 3]);
            }
        }
        float sdl = 0.f;
        #pragma unroll
        for (int i = 0; i < CH; i++) {
            const float sp = softplusf(acc[i]);
            sdl += sp;
            rdlx[i] = sp * rx[i];
            e[i] = __expf(-sp);
        }
        sdl_sh[t] = sdl;
    }
    // ---- detect integer-An structure (block-uniform) ----
    bool fast = true;
    #pragma unroll
    for (int n = 0; n < DS; n++)
        fast = fast && (fabsf(__expf(A_log[d * DS + n]) - (float)(n + 1)) < 1e-3f);
    const float* Bbase = xdb + (size_t)DR * LL;
    const float* Cbase = Bbase + (size_t)DS * LL;
    float y[CH];
    const int n2 = t & 15, sg = t >> 4;

    if (fast) {
        float pw[CH];
        #pragma unroll
        for (int i = 0; i < CH; i++) pw[i] = 1.f;
        // ---- phase1: local scans (h_in = 0), decay via power chain ----
        #pragma unroll 4
        for (int n = 0; n < DS; n++) {
            const float* bp = Bbase + (size_t)n * LL + l0;
            float hn = 0.f;
            #pragma unroll
            for (int j = 0; j < 2; j++) {
                const float4 bv = *(const float4*)(bp + 4 * j);
                pw[4 * j + 0] *= e[4 * j + 0];
                hn = fmaf(pw[4 * j + 0], hn, rdlx[4 * j + 0] * bv.x);
                pw[4 * j + 1] *= e[4 * j + 1];
                hn = fmaf(pw[4 * j + 1], hn, rdlx[4 * j + 1] * bv.y);
                pw[4 * j + 2] *= e[4 * j + 2];
                hn = fmaf(pw[4 * j + 2], hn, rdlx[4 * j + 2] * bv.z);
                pw[4 * j + 3] *= e[4 * j + 3];
                hn = fmaf(pw[4 * j + 3], hn, rdlx[4 * j + 3] * bv.w);
            }
            Ssh[n * (NCH + 1) + t] = hn;
        }
        __syncthreads();
        // ---- phase2a: per-(n2, segment) compose (P,S) ----
        {
            const float Ann = -(float)(n2 + 1);
            float P = 1.f, S = 0.f;
            #pragma unroll
            for (int k = 0; k < 16; k++) {
                const int c = sg * 16 + k;
                const float p = __expf(Ann * sdl_sh[c]);
                const float s = Ssh[n2 * (NCH + 1) + c];
                S = fmaf(p, S, s);
                P *= p;
            }
            Pseg[n2 * (SEG + 1) + sg] = P;
            Sseg[n2 * (SEG + 1) + sg] = S;
        }
        __syncthreads();
        // ---- phase2b: 16 threads scan 32 segments each ----
        if (t < DS) {
            float h = 0.f;
            #pragma unroll 4
            for (int c2 = 0; c2 < SEG; c2++) {
                const float p = Pseg[t * (SEG + 1) + c2];
                const float s = Sseg[t * (SEG + 1) + c2];
                Sseg[t * (SEG + 1) + c2] = h;
                h = fmaf(p, h, s);
            }
        }
        __syncthreads();
        // ---- phase2c: replay within segment -> h_in per chunk ----
        {
            const float Ann = -(float)(n2 + 1);
            float h = Sseg[n2 * (SEG + 1) + sg];
            #pragma unroll
            for (int k = 0; k < 16; k++) {
                const int c = sg * 16 + k;
                const float p = __expf(Ann * sdl_sh[c]);
                const float s = Ssh[n2 * (NCH + 1) + c];
                Ssh[n2 * (NCH + 1) + c] = h;
                h = fmaf(p, h, s);
            }
        }
        __syncthreads();
        // ---- phase3: re-scan from h_in, y = sum_n h*C ----
        #pragma unroll
        for (int i = 0; i < CH; i++) { y[i] = 0.f; pw[i] = 1.f; }
        #pragma unroll 4
        for (int n = 0; n < DS; n++) {
            const float* bp = Bbase + (size_t)n * LL + l0;
            const float* cp = Cbase + (size_t)n * LL + l0;
            float hn = Ssh[n * (NCH + 1) + t];
            #pragma unroll
            for (int j = 0; j < 2; j++) {
                const float4 bv = *(const float4*)(bp + 4 * j);
                const float4 cv = *(const float4*)(cp + 4 * j);
                pw[4 * j + 0] *= e[4 * j + 0];
                hn = fmaf(pw[4 * j + 0], hn, rdlx[4 * j + 0] * bv.x);
                y[4 * j + 0] = fmaf(hn, cv.x, y[4 * j + 0]);
                pw[4 * j + 1] *= e[4 * j + 1];
                hn = fmaf(pw[4 * j + 1], hn, rdlx[4 * j + 1] * bv.y);
                y[4 * j + 1] = fmaf(hn, cv.y, y[4 * j + 1]);
                pw[4 * j + 2] *= e[4 * j + 2];
                hn = fmaf(pw[4 * j + 2], hn, rdlx[4 * j + 2] * bv.z);
                y[4 * j + 2] = fmaf(hn, cv.z, y[4 * j + 2]);
                pw[4 * j + 3] *= e[4 * j + 3];
                hn = fmaf(pw[4 * j + 3], hn, rdlx[4 * j + 3] * bv.w);
                y[4 * j + 3] = fmaf(hn, cv.w, y[4 * j + 3]);
            }
        }
    } else {
        // ---- generic fallback: rdl recovered as -ln(e) (cold path) ----
        float rdl[CH];
        #pragma unroll
        for (int i = 0; i < CH; i++) rdl[i] = -0.69314718f * log2f(e[i]);
        #pragma unroll 4
        for (int n = 0; n < DS; n++) {
            const float An = -__expf(A_log[d * DS + n]);
            const float* bp = Bbase + (size_t)n * LL + l0;
            float hn = 0.f;
            #pragma unroll
            for (int j = 0; j < 2; j++) {
                const float4 bv = *(const float4*)(bp + 4 * j);
                hn = fmaf(__expf(rdl[4 * j + 0] * An), hn, rdlx[4 * j + 0] * bv.x);
                hn = fmaf(__expf(rdl[4 * j + 1] * An), hn, rdlx[4 * j + 1] * bv.y);
                hn = fmaf(__expf(rdl[4 * j + 2] * An), hn, rdlx[4 * j + 2] * bv.z);
                hn = fmaf(__expf(rdl[4 * j + 3] * An), hn, rdlx[4 * j + 3] * bv.w);
            }
            Ssh[n * (NCH + 1) + t] = hn;
        }
        __syncthreads();
        {
            const float Ann = -__expf(A_log[d * DS + n2]);
            float P = 1.f, S = 0.f;
            #pragma unroll
            for (int k = 0; k < 16; k++) {
                const int c = sg * 16 + k;
                const float p = __expf(Ann * sdl_sh[c]);
                const float s = Ssh[n2 * (NCH + 1) + c];
                S = fmaf(p, S, s);
                P *= p;
            }
            Pseg[n2 * (SEG + 1) + sg] = P;
            Sseg[n2 * (SEG + 1) + sg] = S;
        }
        __syncthreads();
        if (t < DS) {
            float h = 0.f;
            #pragma unroll 4
            for (int c2 = 0; c2 < SEG; c2++) {
                const float p = Pseg[t * (SEG + 1) + c2];
                const float s = Sseg[t * (SEG + 1) + c2];
                Sseg[t * (SEG + 1) + c2] = h;
                h = fmaf(p, h, s);
            }
        }
        __syncthreads();
        {
            const float Ann = -__expf(A_log[d * DS + n2]);
            float h = Sseg[n2 * (SEG + 1) + sg];
            #pragma unroll
            for (int k = 0; k < 16; k++) {
                const int c = sg * 16 + k;
                const float p = __expf(Ann * sdl_sh[c]);
                const float s = Ssh[n2 * (NCH + 1) + c];
                Ssh[n2 * (NCH + 1) + c] = h;
                h = fmaf(p, h, s);
            }
        }
        __syncthreads();
        #pragma unroll
        for (int i = 0; i < CH; i++) y[i] = 0.f;
        #pragma unroll 4
        for (int n = 0; n < DS; n++) {
            const float An = -__expf(A_log[d * DS + n]);
            const float* bp = Bbase + (size_t)n * LL + l0;
            const float* cp = Cbase + (size_t)n * LL + l0;
            float hn = Ssh[n * (NCH + 1) + t];
            #pragma unroll
            for (int j = 0; j < 2; j++) {
                const float4 bv = *(const float4*)(bp + 4 * j);
                const float4 cv = *(const float4*)(cp + 4 * j);
                hn = fmaf(__expf(rdl[4 * j + 0] * An), hn, rdlx[4 * j + 0] * bv.x);
                y[4 * j + 0] = fmaf(hn, cv.x, y[4 * j + 0]);
                hn = fmaf(__expf(rdl[4 * j + 1] * An), hn, rdlx[4 * j + 1] * bv.y);
                y[4 * j + 1] = fmaf(hn, cv.y, y[4 * j + 1]);
                hn = fmaf(__expf(rdl[4 * j + 2] * An), hn, rdlx[4 * j + 2] * bv.z);
                y[4 * j + 2] = fmaf(hn, cv.z, y[4 * j + 2]);
                hn = fmaf(__expf(rdl[4 * j + 3] * An), hn, rdlx[4 * j + 3] * bv.w);
                y[4 * j + 3] = fmaf(hn, cv.w, y[4 * j + 3]);
            }
        }
    }
    // ---- gate: recompute rx from L2-warm x reload, then
    //      y_gated = (y + D*rx) * silu(z), bf16 out ----
    const float Dd = ((zi >= BB) ? D1 : D0)[d];
    const float* z_g = zbuf + (size_t)blk * LL + l0;
    unsigned short* y_g = yb + (size_t)blk * LL + l0;
    {
        float xv[CH + 3];
        if (t > 0) {
            const float4 hm = *(const float4*)(x_g + l0 - 4);
            xv[0] = hm.y; xv[1] = hm.z; xv[2] = hm.w;
        } else { xv[0] = 0.f; xv[1] = 0.f; xv[2] = 0.f; }
        #pragma unroll
        for (int j = 0; j < 2; j++) {
            const float4 v = *(const float4*)(x_g + l0 + 4 * j);
            xv[4 * j + 3] = v.x; xv[4 * j + 4] = v.y;
            xv[4 * j + 5] = v.z; xv[4 * j + 6] = v.w;
        }
        #pragma unroll
        for (int j = 0; j < 2; j++) {
            const float4 zv = *(const float4*)(z_g + 4 * j);
            ushort4 r;
            #pragma unroll
            for (int q = 0; q < 4; q++) {
                const int i = 4 * j + q;
                const float rxi = siluf(w0 * xv[i] + w1 * xv[i + 1] + w2 * xv[i + 2] + w3 * xv[i + 3] + cbias);
                const float zq = (q == 0) ? zv.x : (q == 1) ? zv.y : (q == 2) ? zv.z : zv.w;
                const float val = (y[i] + Dd * rxi) * siluf(zq);
                ((unsigned short*)&r)[q] = f2bf(val);
            }
            *(ushort4*)(y_g + 4 * j) = r;
        }
    }
}

extern "C" void kernel_launch(void* const* d_in, const int* in_sizes, int n_in,
                              void* d_out, int out_size, void* d_ws, size_t ws_size,
                              hipStream_t stream)
{
    (void)in_sizes; (void)n_in; (void)out_size; (void)ws_size;
    auto fp = [&](int i) { return (const float*)d_in[i]; };
    const float *pan = fp(0), *ms = fp(1);
    const float *nwp = fp(2), *nbp = fp(3), *nwm = fp(4), *nbm = fp(5);
    const float *Winp = fp(6), *Winm = fp(7), *Wzp = fp(8), *Wzm = fp(9);
    const float *cwp = fp(10), *cbp = fp(11), *cwm = fp(12), *cbm = fp(13);
    const float *Wxp = fp(14), *Wxm = fp(15);
    const float *Wdtp = fp(16), *Wdtm = fp(17), *bdtp = fp(18), *bdtm = fp(19);
    const float *Alog = fp(20), *Dp = fp(21), *Dm = fp(22);
    const float *Woutp = fp(23), *Woutm = fp(24);

    float* ws = (float*)d_ws;
    unsigned short* x3b = (unsigned short*)ws;            // NZ*CC*LL bf16
    float* xpre = ws + (size_t)NZ * CC * LL / 2;          // NZ*DI*LL f32
    float* zbuf = xpre + (size_t)NZ * DI * LL;            // NZ*DI*LL f32 (z)
    float* xdbl = zbuf + (size_t)NZ * DI * LL;            // NZ*DX*LL f32
    unsigned short* yb = (unsigned short*)(xdbl + (size_t)NZ * DX * LL); // NZ*DI*LL bf16
    unsigned short* wb = yb + (size_t)NZ * DI * LL;       // 217088 bf16
    float* out = (float*)d_out;

    convert_w_kernel<<<dim3(848), 256, 0, stream>>>(Winp, Winm, Wzp, Wzm, Woutp, Woutm, Wxp, Wxm, wb);
    layernorm_kernel<<<dim3(LL / 64, NZ), 256, 0, stream>>>(pan, ms, nwp, nbp, nwm, nbm, x3b);
    gemm_inz_mfma<<<dim3(LL / 64, 8, NZ), 256, 0, stream>>>(wb, x3b, xpre, zbuf);
    gemm_x_mfma<<<dim3(LL / 64, 1, NZ), 256, 0, stream>>>(wb, xpre, cwp, cbp, cwm, cbm, xdbl);
    scan_fused<<<dim3(NZ * DI), 512, 0, stream>>>(xpre, xdbl, Alog, Wdtp, Wdtm, bdtp, bdtm,
                                                  cwp, cbp, cwm, cbm, Dp, Dm, zbuf, yb);
    gemm_out_mfma<<<dim3(LL / 64, 2, NZ), 256, 0, stream>>>(wb, yb, out);
}

// Round 15
// 188.676 us; speedup vs baseline: 1.0103x; 1.0103x over previous
//
#include <hip/hip_runtime.h>
#include <hip/hip_bf16.h>

// Problem constants
constexpr int BB = 2;        // batch
constexpr int CC = 128;      // channels
constexpr int LL = 4096;     // H*W sequence length
constexpr int DI = 256;      // d_inner
constexpr int DS = 16;       // d_state
constexpr int DR = 8;        // dt_rank
constexpr int DX = 40;       // dt_rank + 2*d_state
constexpr int NZ = 2 * BB;   // branches * batch
constexpr int CH = 8;        // scan chunk length (per thread)
constexpr int NCH = LL / CH; // 512 chunks == threads per scan WG
constexpr int SEG = 32;      // phase2 segments (16 chunks each)

typedef short bf16x8 __attribute__((ext_vector_type(8)));
typedef float f32x4 __attribute__((ext_vector_type(4)));

__device__ __forceinline__ unsigned short f2bf(float x) {
    __hip_bfloat16 h = __float2bfloat16(x);
    return *(unsigned short*)&h;
}
__device__ __forceinline__ float bflo(unsigned u) { return __uint_as_float(u << 16); }
__device__ __forceinline__ float bfhi(unsigned u) { return __uint_as_float(u & 0xffff0000u); }
__device__ __forceinline__ float fast_rcp(float x) { return __builtin_amdgcn_rcpf(x); }
__device__ __forceinline__ float siluf(float x) { return x * fast_rcp(1.f + __expf(-x)); }
__device__ __forceinline__ float softplusf(float x) {
    const float z = exp2f(x * 1.44269504f);
    return (x > 20.f) ? x : 0.69314718f * log2f(1.f + z);
}

// ---------------- Weight fp32 -> bf16 conversion (once per call) -------------
__global__ __launch_bounds__(256) void convert_w_kernel(
    const float* __restrict__ Winp, const float* __restrict__ Winm,
    const float* __restrict__ Wzp, const float* __restrict__ Wzm,
    const float* __restrict__ Woutp, const float* __restrict__ Woutm,
    const float* __restrict__ Wxp, const float* __restrict__ Wxm,
    unsigned short* __restrict__ dst)
{
    const int i = blockIdx.x * 256 + threadIdx.x;
    const float* src; int off;
    if (i < 32768)       { src = Winp;  off = i; }
    else if (i < 65536)  { src = Winm;  off = i - 32768; }
    else if (i < 98304)  { src = Wzp;   off = i - 65536; }
    else if (i < 131072) { src = Wzm;   off = i - 98304; }
    else if (i < 163840) { src = Woutp; off = i - 131072; }
    else if (i < 196608) { src = Woutm; off = i - 163840; }
    else if (i < 206848) { src = Wxp;   off = i - 196608; }
    else                 { src = Wxm;   off = i - 206848; }
    dst[i] = f2bf(src[off]);
}

// ---------------- LayerNorm over C -> bf16 x3, (zi, C, L) layout -------------
__global__ __launch_bounds__(256) void layernorm_kernel(
    const float* __restrict__ pan, const float* __restrict__ ms,
    const float* __restrict__ wpan, const float* __restrict__ bpan,
    const float* __restrict__ wms, const float* __restrict__ bms,
    unsigned short* __restrict__ x3b)
{
    const int zi = blockIdx.y;
    const int br = zi >> 1, b = zi & 1;
    const float* inp = br ? ms : pan;
    const float* wp = br ? wms : wpan;
    const float* bp = br ? bms : bpan;
    const int l0 = blockIdx.x * 64;
    const int t = threadIdx.x;
    const int lo = t & 63, c4 = t >> 6;
    const float* base = inp + (size_t)b * CC * LL + l0 + lo;
    float vals[32];
    float s = 0.f, s2 = 0.f;
    #pragma unroll
    for (int i = 0; i < 32; i++) {
        const int c = c4 * 32 + i;
        const float v = base[(size_t)c * LL];
        vals[i] = v; s += v; s2 += v * v;
    }
    __shared__ float red[2][4][64];
    red[0][c4][lo] = s; red[1][c4][lo] = s2;
    __syncthreads();
    const float S  = red[0][0][lo] + red[0][1][lo] + red[0][2][lo] + red[0][3][lo];
    const float S2 = red[1][0][lo] + red[1][1][lo] + red[1][2][lo] + red[1][3][lo];
    const float mu = S * (1.f / CC);
    const float var = S2 * (1.f / CC) - mu * mu;
    const float rstd = rsqrtf(var + 1e-5f);
    unsigned short* out = x3b + (size_t)zi * CC * LL + l0 + lo;
    #pragma unroll
    for (int i = 0; i < 32; i++) {
        const int c = c4 * 32 + i;
        out[(size_t)c * LL] = f2bf((vals[i] - mu) * rstd * wp[c] + bp[c]);
    }
}

// ================= MFMA bf16 GEMMs =================
// Fused W_in + W_z: my 0..3 -> W_in -> xpre (fp32); my 4..7 -> W_z -> zb16 (bf16).
__global__ __launch_bounds__(256) void gemm_inz_mfma(
    const unsigned short* __restrict__ wb, const unsigned short* __restrict__ x3b,
    float* __restrict__ xpre, unsigned short* __restrict__ zb16)
{
    const int zi = blockIdx.z;
    const int my = blockIdx.y;
    const unsigned short* W = wb + (my >= 4 ? 65536 : 0) + (zi >= BB ? 32768 : 0);
    const int mbase = (my & 3) * 64;
    const unsigned short* Xb = x3b + (size_t)zi * CC * LL;
    const int n0 = blockIdx.x * 64;
    const int t = threadIdx.x;
    const int w = t >> 6, ln = t & 63;
    const int nf = ln & 15, qb = ln >> 4;
    bf16x8 afrag[4];
    const int mrow = mbase + w * 16 + nf;
    #pragma unroll
    for (int c = 0; c < 4; c++)
        afrag[c] = *(const bf16x8*)(W + (size_t)mrow * CC + c * 32 + qb * 8);
    __shared__ unsigned short Bs[64][40];
    unsigned* Bw = (unsigned*)Bs;
    f32x4 acc[4] = {};
    const int kp = t >> 4, n4 = (t & 15) * 4;
    #pragma unroll
    for (int kc = 0; kc < 4; kc++) {
        const ushort4 a0 = *(const ushort4*)(Xb + (size_t)(kc * 32 + 2 * kp) * LL + n0 + n4);
        const ushort4 a1 = *(const ushort4*)(Xb + (size_t)(kc * 32 + 2 * kp + 1) * LL + n0 + n4);
        if (kc) __syncthreads();
        Bw[(n4 + 0) * 20 + kp] = (unsigned)a0.x | ((unsigned)a1.x << 16);
        Bw[(n4 + 1) * 20 + kp] = (unsigned)a0.y | ((unsigned)a1.y << 16);
        Bw[(n4 + 2) * 20 + kp] = (unsigned)a0.z | ((unsigned)a1.z << 16);
        Bw[(n4 + 3) * 20 + kp] = (unsigned)a0.w | ((unsigned)a1.w << 16);
        __syncthreads();
        #pragma unroll
        for (int ns = 0; ns < 4; ns++) {
            const bf16x8 bf = *(const bf16x8*)(&Bs[ns * 16 + nf][qb * 8]);
            acc[ns] = __builtin_amdgcn_mfma_f32_16x16x32_bf16(afrag[kc], bf, acc[ns], 0, 0, 0);
        }
    }
    if (my >= 4) {
        #pragma unroll
        for (int ns = 0; ns < 4; ns++)
            #pragma unroll
            for (int r = 0; r < 4; r++) {
                const int m = mbase + w * 16 + qb * 4 + r;
                zb16[((size_t)zi * DI + m) * LL + n0 + ns * 16 + nf] = f2bf(acc[ns][r]);
            }
    } else {
        #pragma unroll
        for (int ns = 0; ns < 4; ns++)
            #pragma unroll
            for (int r = 0; r < 4; r++) {
                const int m = mbase + w * 16 + qb * 4 + r;
                xpre[((size_t)zi * DI + m) * LL + n0 + ns * 16 + nf] = acc[ns][r];
            }
    }
}

// W_x GEMM with fused conv+SiLU staging; output xdbl in BF16 (dt/B/C rows).
__global__ __launch_bounds__(256) void gemm_x_mfma(
    const unsigned short* __restrict__ wb, const float* __restrict__ xpre,
    const float* __restrict__ cw0, const float* __restrict__ cb0,
    const float* __restrict__ cw1, const float* __restrict__ cb1,
    unsigned short* __restrict__ xdbl16)
{
    const int zi = blockIdx.z;
    const unsigned short* W = wb + 196608 + (zi >= BB ? 10240 : 0);
    const float* cw = (zi >= BB) ? cw1 : cw0;
    const float* cb = (zi >= BB) ? cb1 : cb0;
    const float* Xb = xpre + (size_t)zi * DI * LL;
    const int n0 = blockIdx.x * 64;
    const int t = threadIdx.x;
    const int w = t >> 6, ln = t & 63;
    const int nf = ln & 15, qb = ln >> 4;
    bf16x8 zfrag;
    #pragma unroll
    for (int j = 0; j < 8; j++) zfrag[j] = 0;
    bf16x8 afrag[8];
    const int mrow = w * 16 + nf;
    #pragma unroll
    for (int c = 0; c < 8; c++)
        afrag[c] = (mrow < DX) ? *(const bf16x8*)(W + (size_t)mrow * DI + c * 32 + qb * 8) : zfrag;
    __shared__ unsigned short Bs[64][40];
    unsigned* Bw = (unsigned*)Bs;
    f32x4 acc[4] = {};
    const int kp = t >> 4, n4 = (t & 15) * 4;
    #pragma unroll
    for (int kc = 0; kc < 8; kc++) {
        float vals[2][4];
        #pragma unroll
        for (int rr = 0; rr < 2; rr++) {
            const int e = kc * 32 + 2 * kp + rr;
            const float* xp = Xb + (size_t)e * LL + n0 + n4;
            const float4 cur = *(const float4*)xp;
            float xm1, xm2, xm3;
            if (n0 + n4 == 0) { xm1 = 0.f; xm2 = 0.f; xm3 = 0.f; }
            else { xm1 = xp[-1]; xm2 = xp[-2]; xm3 = xp[-3]; }
            const float w0 = cw[e * 4 + 0], w1 = cw[e * 4 + 1];
            const float w2 = cw[e * 4 + 2], w3 = cw[e * 4 + 3];
            const float bias = cb[e];
            vals[rr][0] = siluf(w0 * xm3 + w1 * xm2 + w2 * xm1 + w3 * cur.x + bias);
            vals[rr][1] = siluf(w0 * xm2 + w1 * xm1 + w2 * cur.x + w3 * cur.y + bias);
            vals[rr][2] = siluf(w0 * xm1 + w1 * cur.x + w2 * cur.y + w3 * cur.z + bias);
            vals[rr][3] = siluf(w0 * cur.x + w1 * cur.y + w2 * cur.z + w3 * cur.w + bias);
        }
        if (kc) __syncthreads();
        #pragma unroll
        for (int j = 0; j < 4; j++)
            Bw[(n4 + j) * 20 + kp] = (unsigned)f2bf(vals[0][j]) | ((unsigned)f2bf(vals[1][j]) << 16);
        __syncthreads();
        #pragma unroll
        for (int ns = 0; ns < 4; ns++) {
            const bf16x8 bf = *(const bf16x8*)(&Bs[ns * 16 + nf][qb * 8]);
            acc[ns] = __builtin_amdgcn_mfma_f32_16x16x32_bf16(afrag[kc], bf, acc[ns], 0, 0, 0);
        }
    }
    #pragma unroll
    for (int ns = 0; ns < 4; ns++)
        #pragma unroll
        for (int r = 0; r < 4; r++) {
            const int m = w * 16 + qb * 4 + r;
            if (m < DX)
                xdbl16[((size_t)zi * DX + m) * LL + n0 + ns * 16 + nf] = f2bf(acc[ns][r]);
        }
}

__global__ __launch_bounds__(256) void gemm_out_mfma(
    const unsigned short* __restrict__ wb, const unsigned short* __restrict__ yb,
    float* __restrict__ outg)
{
    const int zi = blockIdx.z;
    const unsigned short* W = wb + 131072 + (zi >= BB ? 32768 : 0);
    const int mbase = blockIdx.y * 64;
    const unsigned short* Xb = yb + (size_t)zi * DI * LL;
    const int n0 = blockIdx.x * 64;
    const int t = threadIdx.x;
    const int w = t >> 6, ln = t & 63;
    const int nf = ln & 15, qb = ln >> 4;
    bf16x8 afrag[8];
    const int mrow = mbase + w * 16 + nf;
    #pragma unroll
    for (int c = 0; c < 8; c++)
        afrag[c] = *(const bf16x8*)(W + (size_t)mrow * DI + c * 32 + qb * 8);
    __shared__ unsigned short Bs[64][40];
    unsigned* Bw = (unsigned*)Bs;
    f32x4 acc[4] = {};
    const int kp = t >> 4, n4 = (t & 15) * 4;
    #pragma unroll
    for (int kc = 0; kc < 8; kc++) {
        const ushort4 a0 = *(const ushort4*)(Xb + (size_t)(kc * 32 + 2 * kp) * LL + n0 + n4);
        const ushort4 a1 = *(const ushort4*)(Xb + (size_t)(kc * 32 + 2 * kp + 1) * LL + n0 + n4);
        if (kc) __syncthreads();
        Bw[(n4 + 0) * 20 + kp] = (unsigned)a0.x | ((unsigned)a1.x << 16);
        Bw[(n4 + 1) * 20 + kp] = (unsigned)a0.y | ((unsigned)a1.y << 16);
        Bw[(n4 + 2) * 20 + kp] = (unsigned)a0.z | ((unsigned)a1.z << 16);
        Bw[(n4 + 3) * 20 + kp] = (unsigned)a0.w | ((unsigned)a1.w << 16);
        __syncthreads();
        #pragma unroll
        for (int ns = 0; ns < 4; ns++) {
            const bf16x8 bf = *(const bf16x8*)(&Bs[ns * 16 + nf][qb * 8]);
            acc[ns] = __builtin_amdgcn_mfma_f32_16x16x32_bf16(afrag[kc], bf, acc[ns], 0, 0, 0);
        }
    }
    #pragma unroll
    for (int ns = 0; ns < 4; ns++)
        #pragma unroll
        for (int r = 0; r < 4; r++) {
            const int m = mbase + w * 16 + qb * 4 + r;
            outg[((size_t)zi * CC + m) * LL + n0 + ns * 16 + nf] = acc[ns][r];
        }
}

// ================= Fully fused selective scan (512 thr, CH=8, bf16 streams) ==
// dt/B/C rows (xdbl16) and z (zb16) are bf16: one uint4 load = 8 elements,
// halving VMEM instructions and L2/HBM bytes vs round-14 fp32 streams.
__global__ __launch_bounds__(512, 8) void scan_fused(
    const float* __restrict__ xpre, const unsigned short* __restrict__ xdbl16,
    const float* __restrict__ A_log,
    const float* __restrict__ Wdt0, const float* __restrict__ Wdt1,
    const float* __restrict__ bdt0, const float* __restrict__ bdt1,
    const float* __restrict__ cw0, const float* __restrict__ cb0,
    const float* __restrict__ cw1, const float* __restrict__ cb1,
    const float* __restrict__ D0, const float* __restrict__ D1,
    const unsigned short* __restrict__ zb16, unsigned short* __restrict__ yb)
{
    const int blk = blockIdx.x;          // zi*DI + d
    const int zi = blk >> 8;
    const int d  = blk & (DI - 1);
    const int t = threadIdx.x;
    const int l0 = t * CH;
    __shared__ float Ssh[DS * (NCH + 1)];   // stride 513
    __shared__ float sdl_sh[NCH];
    __shared__ float Pseg[DS * (SEG + 1)];  // stride 33
    __shared__ float Sseg[DS * (SEG + 1)];
    const float* x_g = xpre + (size_t)blk * LL;
    const unsigned short* xdb = xdbl16 + (size_t)zi * DX * LL;
    const float* Wdt = (zi >= BB) ? Wdt1 : Wdt0;
    const float* bdt = (zi >= BB) ? bdt1 : bdt0;
    const float dbias = bdt[d];
    const float* cw = (zi >= BB) ? cw1 : cw0;
    const float* cb = (zi >= BB) ? cb1 : cb0;
    const float w0 = cw[d * 4 + 0], w1 = cw[d * 4 + 1];
    const float w2 = cw[d * 4 + 2], w3 = cw[d * 4 + 3];
    const float cbias = cb[d];
    float e[CH], rdlx[CH];
    {
        // ---- x + conv + SiLU (prolog-local rx) ----
        float rx[CH];
        {
            float xv[CH + 3];
            if (t > 0) {
                const float4 hm = *(const float4*)(x_g + l0 - 4);
                xv[0] = hm.y; xv[1] = hm.z; xv[2] = hm.w;
            } else { xv[0] = 0.f; xv[1] = 0.f; xv[2] = 0.f; }
            #pragma unroll
            for (int j = 0; j < 2; j++) {
                const float4 v = *(const float4*)(x_g + l0 + 4 * j);
                xv[4 * j + 3] = v.x; xv[4 * j + 4] = v.y;
                xv[4 * j + 5] = v.z; xv[4 * j + 6] = v.w;
            }
            #pragma unroll
            for (int i = 0; i < CH; i++)
                rx[i] = siluf(w0 * xv[i] + w1 * xv[i + 1] + w2 * xv[i + 2] + w3 * xv[i + 3] + cbias);
        }
        // ---- delta pre-activation from bf16 dt rows ----
        float acc[CH];
        #pragma unroll
        for (int i = 0; i < CH; i++) acc[i] = dbias;
        #pragma unroll
        for (int r = 0; r < DR; r++) {
            const float wr = Wdt[d * DR + r];
            const uint4 v = *(const uint4*)(xdb + (size_t)r * LL + l0);
            acc[0] = fmaf(wr, bflo(v.x), acc[0]); acc[1] = fmaf(wr, bfhi(v.x), acc[1]);
            acc[2] = fmaf(wr, bflo(v.y), acc[2]); acc[3] = fmaf(wr, bfhi(v.y), acc[3]);
            acc[4] = fmaf(wr, bflo(v.z), acc[4]); acc[5] = fmaf(wr, bfhi(v.z), acc[5]);
            acc[6] = fmaf(wr, bflo(v.w), acc[6]); acc[7] = fmaf(wr, bfhi(v.w), acc[7]);
        }
        float sdl = 0.f;
        #pragma unroll
        for (int i = 0; i < CH; i++) {
            const float sp = softplusf(acc[i]);
            sdl += sp;
            rdlx[i] = sp * rx[i];
            e[i] = __expf(-sp);
        }
        sdl_sh[t] = sdl;
    }
    // ---- detect integer-An structure (block-uniform) ----
    bool fast = true;
    #pragma unroll
    for (int n = 0; n < DS; n++)
        fast = fast && (fabsf(__expf(A_log[d * DS + n]) - (float)(n + 1)) < 1e-3f);
    const unsigned short* Bbase = xdb + (size_t)DR * LL;
    const unsigned short* Cbase = Bbase + (size_t)DS * LL;
    float y[CH];
    const int n2 = t & 15, sg = t >> 4;

    if (fast) {
        float pw[CH];
        #pragma unroll
        for (int i = 0; i < CH; i++) pw[i] = 1.f;
        // ---- phase1: local scans (h_in = 0), decay via power chain ----
        #pragma unroll 4
        for (int n = 0; n < DS; n++) {
            const uint4 bv = *(const uint4*)(Bbase + (size_t)n * LL + l0);
            float hn = 0.f;
            pw[0] *= e[0]; hn = fmaf(pw[0], hn, rdlx[0] * bflo(bv.x));
            pw[1] *= e[1]; hn = fmaf(pw[1], hn, rdlx[1] * bfhi(bv.x));
            pw[2] *= e[2]; hn = fmaf(pw[2], hn, rdlx[2] * bflo(bv.y));
            pw[3] *= e[3]; hn = fmaf(pw[3], hn, rdlx[3] * bfhi(bv.y));
            pw[4] *= e[4]; hn = fmaf(pw[4], hn, rdlx[4] * bflo(bv.z));
            pw[5] *= e[5]; hn = fmaf(pw[5], hn, rdlx[5] * bfhi(bv.z));
            pw[6] *= e[6]; hn = fmaf(pw[6], hn, rdlx[6] * bflo(bv.w));
            pw[7] *= e[7]; hn = fmaf(pw[7], hn, rdlx[7] * bfhi(bv.w));
            Ssh[n * (NCH + 1) + t] = hn;
        }
        __syncthreads();
        // ---- phase2a: per-(n2, segment) compose (P,S) ----
        {
            const float Ann = -(float)(n2 + 1);
            float P = 1.f, S = 0.f;
            #pragma unroll
            for (int k = 0; k < 16; k++) {
                const int c = sg * 16 + k;
                const float p = __expf(Ann * sdl_sh[c]);
                const float s = Ssh[n2 * (NCH + 1) + c];
                S = fmaf(p, S, s);
                P *= p;
            }
            Pseg[n2 * (SEG + 1) + sg] = P;
            Sseg[n2 * (SEG + 1) + sg] = S;
        }
        __syncthreads();
        // ---- phase2b: 16 threads scan 32 segments each ----
        if (t < DS) {
            float h = 0.f;
            #pragma unroll 4
            for (int c2 = 0; c2 < SEG; c2++) {
                const float p = Pseg[t * (SEG + 1) + c2];
                const float s = Sseg[t * (SEG + 1) + c2];
                Sseg[t * (SEG + 1) + c2] = h;
                h = fmaf(p, h, s);
            }
        }
        __syncthreads();
        // ---- phase2c: replay within segment -> h_in per chunk ----
        {
            const float Ann = -(float)(n2 + 1);
            float h = Sseg[n2 * (SEG + 1) + sg];
            #pragma unroll
            for (int k = 0; k < 16; k++) {
                const int c = sg * 16 + k;
                const float p = __expf(Ann * sdl_sh[c]);
                const float s = Ssh[n2 * (NCH + 1) + c];
                Ssh[n2 * (NCH + 1) + c] = h;
                h = fmaf(p, h, s);
            }
        }
        __syncthreads();
        // ---- phase3: re-scan from h_in, y = sum_n h*C ----
        #pragma unroll
        for (int i = 0; i < CH; i++) { y[i] = 0.f; pw[i] = 1.f; }
        #pragma unroll 4
        for (int n = 0; n < DS; n++) {
            const uint4 bv = *(const uint4*)(Bbase + (size_t)n * LL + l0);
            const uint4 cv = *(const uint4*)(Cbase + (size_t)n * LL + l0);
            float hn = Ssh[n * (NCH + 1) + t];
            pw[0] *= e[0]; hn = fmaf(pw[0], hn, rdlx[0] * bflo(bv.x)); y[0] = fmaf(hn, bflo(cv.x), y[0]);
            pw[1] *= e[1]; hn = fmaf(pw[1], hn, rdlx[1] * bfhi(bv.x)); y[1] = fmaf(hn, bfhi(cv.x), y[1]);
            pw[2] *= e[2]; hn = fmaf(pw[2], hn, rdlx[2] * bflo(bv.y)); y[2] = fmaf(hn, bflo(cv.y), y[2]);
            pw[3] *= e[3]; hn = fmaf(pw[3], hn, rdlx[3] * bfhi(bv.y)); y[3] = fmaf(hn, bfhi(cv.y), y[3]);
            pw[4] *= e[4]; hn = fmaf(pw[4], hn, rdlx[4] * bflo(bv.z)); y[4] = fmaf(hn, bflo(cv.z), y[4]);
            pw[5] *= e[5]; hn = fmaf(pw[5], hn, rdlx[5] * bfhi(bv.z)); y[5] = fmaf(hn, bfhi(cv.z), y[5]);
            pw[6] *= e[6]; hn = fmaf(pw[6], hn, rdlx[6] * bflo(bv.w)); y[6] = fmaf(hn, bflo(cv.w), y[6]);
            pw[7] *= e[7]; hn = fmaf(pw[7], hn, rdlx[7] * bfhi(bv.w)); y[7] = fmaf(hn, bfhi(cv.w), y[7]);
        }
    } else {
        // ---- generic fallback: rdl recovered as -ln(e) (cold path) ----
        float rdl[CH];
        #pragma unroll
        for (int i = 0; i < CH; i++) rdl[i] = -0.69314718f * log2f(e[i]);
        #pragma unroll 4
        for (int n = 0; n < DS; n++) {
            const float An = -__expf(A_log[d * DS + n]);
            const uint4 bv = *(const uint4*)(Bbase + (size_t)n * LL + l0);
            float hn = 0.f;
            hn = fmaf(__expf(rdl[0] * An), hn, rdlx[0] * bflo(bv.x));
            hn = fmaf(__expf(rdl[1] * An), hn, rdlx[1] * bfhi(bv.x));
            hn = fmaf(__expf(rdl[2] * An), hn, rdlx[2] * bflo(bv.y));
            hn = fmaf(__expf(rdl[3] * An), hn, rdlx[3] * bfhi(bv.y));
            hn = fmaf(__expf(rdl[4] * An), hn, rdlx[4] * bflo(bv.z));
            hn = fmaf(__expf(rdl[5] * An), hn, rdlx[5] * bfhi(bv.z));
            hn = fmaf(__expf(rdl[6] * An), hn, rdlx[6] * bflo(bv.w));
            hn = fmaf(__expf(rdl[7] * An), hn, rdlx[7] * bfhi(bv.w));
            Ssh[n * (NCH + 1) + t] = hn;
        }
        __syncthreads();
        {
            const float Ann = -__expf(A_log[d * DS + n2]);
            float P = 1.f, S = 0.f;
            #pragma unroll
            for (int k = 0; k < 16; k++) {
                const int c = sg * 16 + k;
                const float p = __expf(Ann * sdl_sh[c]);
                const float s = Ssh[n2 * (NCH + 1) + c];
                S = fmaf(p, S, s);
                P *= p;
            }
            Pseg[n2 * (SEG + 1) + sg] = P;
            Sseg[n2 * (SEG + 1) + sg] = S;
        }
        __syncthreads();
        if (t < DS) {
            float h = 0.f;
            #pragma unroll 4
            for (int c2 = 0; c2 < SEG; c2++) {
                const float p = Pseg[t * (SEG + 1) + c2];
                const float s = Sseg[t * (SEG + 1) + c2];
                Sseg[t * (SEG + 1) + c2] = h;
                h = fmaf(p, h, s);
            }
        }
        __syncthreads();
        {
            const float Ann = -__expf(A_log[d * DS + n2]);
            float h = Sseg[n2 * (SEG + 1) + sg];
            #pragma unroll
            for (int k = 0; k < 16; k++) {
                const int c = sg * 16 + k;
                const float p = __expf(Ann * sdl_sh[c]);
                const float s = Ssh[n2 * (NCH + 1) + c];
                Ssh[n2 * (NCH + 1) + c] = h;
                h = fmaf(p, h, s);
            }
        }
        __syncthreads();
        #pragma unroll
        for (int i = 0; i < CH; i++) y[i] = 0.f;
        #pragma unroll 4
        for (int n = 0; n < DS; n++) {
            const float An = -__expf(A_log[d * DS + n]);
            const uint4 bv = *(const uint4*)(Bbase + (size_t)n * LL + l0);
            const uint4 cv = *(const uint4*)(Cbase + (size_t)n * LL + l0);
            float hn = Ssh[n * (NCH + 1) + t];
            hn = fmaf(__expf(rdl[0] * An), hn, rdlx[0] * bflo(bv.x)); y[0] = fmaf(hn, bflo(cv.x), y[0]);
            hn = fmaf(__expf(rdl[1] * An), hn, rdlx[1] * bfhi(bv.x)); y[1] = fmaf(hn, bfhi(cv.x), y[1]);
            hn = fmaf(__expf(rdl[2] * An), hn, rdlx[2] * bflo(bv.y)); y[2] = fmaf(hn, bflo(cv.y), y[2]);
            hn = fmaf(__expf(rdl[3] * An), hn, rdlx[3] * bfhi(bv.y)); y[3] = fmaf(hn, bfhi(cv.y), y[3]);
            hn = fmaf(__expf(rdl[4] * An), hn, rdlx[4] * bflo(bv.z)); y[4] = fmaf(hn, bflo(cv.z), y[4]);
            hn = fmaf(__expf(rdl[5] * An), hn, rdlx[5] * bfhi(bv.z)); y[5] = fmaf(hn, bfhi(cv.z), y[5]);
            hn = fmaf(__expf(rdl[6] * An), hn, rdlx[6] * bflo(bv.w)); y[6] = fmaf(hn, bflo(cv.w), y[6]);
            hn = fmaf(__expf(rdl[7] * An), hn, rdlx[7] * bfhi(bv.w)); y[7] = fmaf(hn, bfhi(cv.w), y[7]);
        }
    }
    // ---- gate: recompute rx from L2-warm x reload; z from bf16 ----
    const float Dd = ((zi >= BB) ? D1 : D0)[d];
    const unsigned short* z_g = zb16 + (size_t)blk * LL + l0;
    unsigned short* y_g = yb + (size_t)blk * LL + l0;
    {
        float xv[CH + 3];
        if (t > 0) {
            const float4 hm = *(const float4*)(x_g + l0 - 4);
            xv[0] = hm.y; xv[1] = hm.z; xv[2] = hm.w;
        } else { xv[0] = 0.f; xv[1] = 0.f; xv[2] = 0.f; }
        #pragma unroll
        for (int j = 0; j < 2; j++) {
            const float4 v = *(const float4*)(x_g + l0 + 4 * j);
            xv[4 * j + 3] = v.x; xv[4 * j + 4] = v.y;
            xv[4 * j + 5] = v.z; xv[4 * j + 6] = v.w;
        }
        const uint4 zv = *(const uint4*)z_g;
        float zf[CH];
        zf[0] = bflo(zv.x); zf[1] = bfhi(zv.x); zf[2] = bflo(zv.y); zf[3] = bfhi(zv.y);
        zf[4] = bflo(zv.z); zf[5] = bfhi(zv.z); zf[6] = bflo(zv.w); zf[7] = bfhi(zv.w);
        ushort4 r0, r1;
        #pragma unroll
        for (int i = 0; i < CH; i++) {
            const float rxi = siluf(w0 * xv[i] + w1 * xv[i + 1] + w2 * xv[i + 2] + w3 * xv[i + 3] + cbias);
            const float val = (y[i] + Dd * rxi) * siluf(zf[i]);
            if (i < 4) ((unsigned short*)&r0)[i] = f2bf(val);
            else       ((unsigned short*)&r1)[i - 4] = f2bf(val);
        }
        *(ushort4*)(y_g + 0) = r0;
        *(ushort4*)(y_g + 4) = r1;
    }
}

extern "C" void kernel_launch(void* const* d_in, const int* in_sizes, int n_in,
                              void* d_out, int out_size, void* d_ws, size_t ws_size,
                              hipStream_t stream)
{
    (void)in_sizes; (void)n_in; (void)out_size; (void)ws_size;
    auto fp = [&](int i) { return (const float*)d_in[i]; };
    const float *pan = fp(0), *ms = fp(1);
    const float *nwp = fp(2), *nbp = fp(3), *nwm = fp(4), *nbm = fp(5);
    const float *Winp = fp(6), *Winm = fp(7), *Wzp = fp(8), *Wzm = fp(9);
    const float *cwp = fp(10), *cbp = fp(11), *cwm = fp(12), *cbm = fp(13);
    const float *Wxp = fp(14), *Wxm = fp(15);
    const float *Wdtp = fp(16), *Wdtm = fp(17), *bdtp = fp(18), *bdtm = fp(19);
    const float *Alog = fp(20), *Dp = fp(21), *Dm = fp(22);
    const float *Woutp = fp(23), *Woutm = fp(24);

    float* ws = (float*)d_ws;
    unsigned short* x3b = (unsigned short*)ws;                 // NZ*CC*LL bf16
    float* xpre = ws + (size_t)NZ * CC * LL / 2;               // NZ*DI*LL f32
    unsigned short* zb16 = (unsigned short*)(xpre + (size_t)NZ * DI * LL);   // NZ*DI*LL bf16
    unsigned short* xdbl16 = zb16 + (size_t)NZ * DI * LL;      // NZ*DX*LL bf16
    unsigned short* yb = xdbl16 + (size_t)NZ * DX * LL;        // NZ*DI*LL bf16
    unsigned short* wb = yb + (size_t)NZ * DI * LL;            // 217088 bf16
    float* out = (float*)d_out;

    convert_w_kernel<<<dim3(848), 256, 0, stream>>>(Winp, Winm, Wzp, Wzm, Woutp, Woutm, Wxp, Wxm, wb);
    layernorm_kernel<<<dim3(LL / 64, NZ), 256, 0, stream>>>(pan, ms, nwp, nbp, nwm, nbm, x3b);
    gemm_inz_mfma<<<dim3(LL / 64, 8, NZ), 256, 0, stream>>>(wb, x3b, xpre, zb16);
    gemm_x_mfma<<<dim3(LL / 64, 1, NZ), 256, 0, stream>>>(wb, xpre, cwp, cbp, cwm, cbm, xdbl16);
    scan_fused<<<dim3(NZ * DI), 512, 0, stream>>>(xpre, xdbl16, Alog, Wdtp, Wdtm, bdtp, bdtm,
                                                  cwp, cbp, cwm, cbm, Dp, Dm, zb16, yb);
    gemm_out_mfma<<<dim3(LL / 64, 2, NZ), 256, 0, stream>>>(wb, yb, out);
}

// Round 17
// 185.973 us; speedup vs baseline: 1.0250x; 1.0145x over previous
//
#include <hip/hip_runtime.h>
#include <hip/hip_bf16.h>

// Problem constants
constexpr int BB = 2;        // batch
constexpr int CC = 128;      // channels
constexpr int LL = 4096;     // H*W sequence length
constexpr int DI = 256;      // d_inner
constexpr int DS = 16;       // d_state
constexpr int DR = 8;        // dt_rank
constexpr int DX = 40;       // dt_rank + 2*d_state
constexpr int NZ = 2 * BB;   // branches * batch
constexpr int CH = 8;        // scan chunk length (per thread)
constexpr int NCH = LL / CH; // 512 chunks == threads per scan WG
constexpr int SEG = 32;      // phase2 segments (16 chunks each)

typedef short bf16x8 __attribute__((ext_vector_type(8)));
typedef float f32x4 __attribute__((ext_vector_type(4)));

__device__ __forceinline__ unsigned short f2bf(float x) {
    __hip_bfloat16 h = __float2bfloat16(x);
    return *(unsigned short*)&h;
}
__device__ __forceinline__ float bflo(unsigned u) { return __uint_as_float(u << 16); }
__device__ __forceinline__ float bfhi(unsigned u) { return __uint_as_float(u & 0xffff0000u); }
__device__ __forceinline__ float fast_rcp(float x) { return __builtin_amdgcn_rcpf(x); }
__device__ __forceinline__ float siluf(float x) { return x * fast_rcp(1.f + __expf(-x)); }
__device__ __forceinline__ float softplusf(float x) {
    const float z = exp2f(x * 1.44269504f);
    return (x > 20.f) ? x : 0.69314718f * log2f(1.f + z);
}

// ---------------- Weight fp32 -> bf16 conversion (once per call) -------------
__global__ __launch_bounds__(256) void convert_w_kernel(
    const float* __restrict__ Winp, const float* __restrict__ Winm,
    const float* __restrict__ Wzp, const float* __restrict__ Wzm,
    const float* __restrict__ Woutp, const float* __restrict__ Woutm,
    const float* __restrict__ Wxp, const float* __restrict__ Wxm,
    unsigned short* __restrict__ dst)
{
    const int i = blockIdx.x * 256 + threadIdx.x;
    const float* src; int off;
    if (i < 32768)       { src = Winp;  off = i; }
    else if (i < 65536)  { src = Winm;  off = i - 32768; }
    else if (i < 98304)  { src = Wzp;   off = i - 65536; }
    else if (i < 131072) { src = Wzm;   off = i - 98304; }
    else if (i < 163840) { src = Woutp; off = i - 131072; }
    else if (i < 196608) { src = Woutm; off = i - 163840; }
    else if (i < 206848) { src = Wxp;   off = i - 196608; }
    else                 { src = Wxm;   off = i - 206848; }
    dst[i] = f2bf(src[off]);
}

// ---------------- LayerNorm over C -> bf16 x3, (zi, C, L) layout -------------
__global__ __launch_bounds__(256) void layernorm_kernel(
    const float* __restrict__ pan, const float* __restrict__ ms,
    const float* __restrict__ wpan, const float* __restrict__ bpan,
    const float* __restrict__ wms, const float* __restrict__ bms,
    unsigned short* __restrict__ x3b)
{
    const int zi = blockIdx.y;
    const int br = zi >> 1, b = zi & 1;
    const float* inp = br ? ms : pan;
    const float* wp = br ? wms : wpan;
    const float* bp = br ? bms : bpan;
    const int l0 = blockIdx.x * 64;
    const int t = threadIdx.x;
    const int lo = t & 63, c4 = t >> 6;
    const float* base = inp + (size_t)b * CC * LL + l0 + lo;
    float vals[32];
    float s = 0.f, s2 = 0.f;
    #pragma unroll
    for (int i = 0; i < 32; i++) {
        const int c = c4 * 32 + i;
        const float v = base[(size_t)c * LL];
        vals[i] = v; s += v; s2 += v * v;
    }
    __shared__ float red[2][4][64];
    red[0][c4][lo] = s; red[1][c4][lo] = s2;
    __syncthreads();
    const float S  = red[0][0][lo] + red[0][1][lo] + red[0][2][lo] + red[0][3][lo];
    const float S2 = red[1][0][lo] + red[1][1][lo] + red[1][2][lo] + red[1][3][lo];
    const float mu = S * (1.f / CC);
    const float var = S2 * (1.f / CC) - mu * mu;
    const float rstd = rsqrtf(var + 1e-5f);
    unsigned short* out = x3b + (size_t)zi * CC * LL + l0 + lo;
    #pragma unroll
    for (int i = 0; i < 32; i++) {
        const int c = c4 * 32 + i;
        out[(size_t)c * LL] = f2bf((vals[i] - mu) * rstd * wp[c] + bp[c]);
    }
}

// ================= MFMA bf16 GEMMs =================
// Fused W_in + W_z: my 0..3 -> W_in -> xpre (fp32); my 4..7 -> W_z -> zb16 (bf16).
__global__ __launch_bounds__(256) void gemm_inz_mfma(
    const unsigned short* __restrict__ wb, const unsigned short* __restrict__ x3b,
    float* __restrict__ xpre, unsigned short* __restrict__ zb16)
{
    const int zi = blockIdx.z;
    const int my = blockIdx.y;
    const unsigned short* W = wb + (my >= 4 ? 65536 : 0) + (zi >= BB ? 32768 : 0);
    const int mbase = (my & 3) * 64;
    const unsigned short* Xb = x3b + (size_t)zi * CC * LL;
    const int n0 = blockIdx.x * 64;
    const int t = threadIdx.x;
    const int w = t >> 6, ln = t & 63;
    const int nf = ln & 15, qb = ln >> 4;
    bf16x8 afrag[4];
    const int mrow = mbase + w * 16 + nf;
    #pragma unroll
    for (int c = 0; c < 4; c++)
        afrag[c] = *(const bf16x8*)(W + (size_t)mrow * CC + c * 32 + qb * 8);
    __shared__ unsigned short Bs[64][40];
    unsigned* Bw = (unsigned*)Bs;
    f32x4 acc[4] = {};
    const int kp = t >> 4, n4 = (t & 15) * 4;
    #pragma unroll
    for (int kc = 0; kc < 4; kc++) {
        const ushort4 a0 = *(const ushort4*)(Xb + (size_t)(kc * 32 + 2 * kp) * LL + n0 + n4);
        const ushort4 a1 = *(const ushort4*)(Xb + (size_t)(kc * 32 + 2 * kp + 1) * LL + n0 + n4);
        if (kc) __syncthreads();
        Bw[(n4 + 0) * 20 + kp] = (unsigned)a0.x | ((unsigned)a1.x << 16);
        Bw[(n4 + 1) * 20 + kp] = (unsigned)a0.y | ((unsigned)a1.y << 16);
        Bw[(n4 + 2) * 20 + kp] = (unsigned)a0.z | ((unsigned)a1.z << 16);
        Bw[(n4 + 3) * 20 + kp] = (unsigned)a0.w | ((unsigned)a1.w << 16);
        __syncthreads();
        #pragma unroll
        for (int ns = 0; ns < 4; ns++) {
            const bf16x8 bf = *(const bf16x8*)(&Bs[ns * 16 + nf][qb * 8]);
            acc[ns] = __builtin_amdgcn_mfma_f32_16x16x32_bf16(afrag[kc], bf, acc[ns], 0, 0, 0);
        }
    }
    if (my >= 4) {
        #pragma unroll
        for (int ns = 0; ns < 4; ns++)
            #pragma unroll
            for (int r = 0; r < 4; r++) {
                const int m = mbase + w * 16 + qb * 4 + r;
                zb16[((size_t)zi * DI + m) * LL + n0 + ns * 16 + nf] = f2bf(acc[ns][r]);
            }
    } else {
        #pragma unroll
        for (int ns = 0; ns < 4; ns++)
            #pragma unroll
            for (int r = 0; r < 4; r++) {
                const int m = mbase + w * 16 + qb * 4 + r;
                xpre[((size_t)zi * DI + m) * LL + n0 + ns * 16 + nf] = acc[ns][r];
            }
    }
}

// W_x GEMM with fused conv+SiLU staging; output xdbl in BF16 (dt/B/C rows).
__global__ __launch_bounds__(256) void gemm_x_mfma(
    const unsigned short* __restrict__ wb, const float* __restrict__ xpre,
    const float* __restrict__ cw0, const float* __restrict__ cb0,
    const float* __restrict__ cw1, const float* __restrict__ cb1,
    unsigned short* __restrict__ xdbl16)
{
    const int zi = blockIdx.z;
    const unsigned short* W = wb + 196608 + (zi >= BB ? 10240 : 0);
    const float* cw = (zi >= BB) ? cw1 : cw0;
    const float* cb = (zi >= BB) ? cb1 : cb0;
    const float* Xb = xpre + (size_t)zi * DI * LL;
    const int n0 = blockIdx.x * 64;
    const int t = threadIdx.x;
    const int w = t >> 6, ln = t & 63;
    const int nf = ln & 15, qb = ln >> 4;
    bf16x8 zfrag;
    #pragma unroll
    for (int j = 0; j < 8; j++) zfrag[j] = 0;
    bf16x8 afrag[8];
    const int mrow = w * 16 + nf;
    #pragma unroll
    for (int c = 0; c < 8; c++)
        afrag[c] = (mrow < DX) ? *(const bf16x8*)(W + (size_t)mrow * DI + c * 32 + qb * 8) : zfrag;
    __shared__ unsigned short Bs[64][40];
    unsigned* Bw = (unsigned*)Bs;
    f32x4 acc[4] = {};
    const int kp = t >> 4, n4 = (t & 15) * 4;
    #pragma unroll
    for (int kc = 0; kc < 8; kc++) {
        float vals[2][4];
        #pragma unroll
        for (int rr = 0; rr < 2; rr++) {
            const int e = kc * 32 + 2 * kp + rr;
            const float* xp = Xb + (size_t)e * LL + n0 + n4;
            const float4 cur = *(const float4*)xp;
            float xm1, xm2, xm3;
            if (n0 + n4 == 0) { xm1 = 0.f; xm2 = 0.f; xm3 = 0.f; }
            else { xm1 = xp[-1]; xm2 = xp[-2]; xm3 = xp[-3]; }
            const float w0 = cw[e * 4 + 0], w1 = cw[e * 4 + 1];
            const float w2 = cw[e * 4 + 2], w3 = cw[e * 4 + 3];
            const float bias = cb[e];
            vals[rr][0] = siluf(w0 * xm3 + w1 * xm2 + w2 * xm1 + w3 * cur.x + bias);
            vals[rr][1] = siluf(w0 * xm2 + w1 * xm1 + w2 * cur.x + w3 * cur.y + bias);
            vals[rr][2] = siluf(w0 * xm1 + w1 * cur.x + w2 * cur.y + w3 * cur.z + bias);
            vals[rr][3] = siluf(w0 * cur.x + w1 * cur.y + w2 * cur.z + w3 * cur.w + bias);
        }
        if (kc) __syncthreads();
        #pragma unroll
        for (int j = 0; j < 4; j++)
            Bw[(n4 + j) * 20 + kp] = (unsigned)f2bf(vals[0][j]) | ((unsigned)f2bf(vals[1][j]) << 16);
        __syncthreads();
        #pragma unroll
        for (int ns = 0; ns < 4; ns++) {
            const bf16x8 bf = *(const bf16x8*)(&Bs[ns * 16 + nf][qb * 8]);
            acc[ns] = __builtin_amdgcn_mfma_f32_16x16x32_bf16(afrag[kc], bf, acc[ns], 0, 0, 0);
        }
    }
    #pragma unroll
    for (int ns = 0; ns < 4; ns++)
        #pragma unroll
        for (int r = 0; r < 4; r++) {
            const int m = w * 16 + qb * 4 + r;
            if (m < DX)
                xdbl16[((size_t)zi * DX + m) * LL + n0 + ns * 16 + nf] = f2bf(acc[ns][r]);
        }
}

__global__ __launch_bounds__(256) void gemm_out_mfma(
    const unsigned short* __restrict__ wb, const unsigned short* __restrict__ yb,
    float* __restrict__ outg)
{
    const int zi = blockIdx.z;
    const unsigned short* W = wb + 131072 + (zi >= BB ? 32768 : 0);
    const int mbase = blockIdx.y * 64;
    const unsigned short* Xb = yb + (size_t)zi * DI * LL;
    const int n0 = blockIdx.x * 64;
    const int t = threadIdx.x;
    const int w = t >> 6, ln = t & 63;
    const int nf = ln & 15, qb = ln >> 4;
    bf16x8 afrag[8];
    const int mrow = mbase + w * 16 + nf;
    #pragma unroll
    for (int c = 0; c < 8; c++)
        afrag[c] = *(const bf16x8*)(W + (size_t)mrow * DI + c * 32 + qb * 8);
    __shared__ unsigned short Bs[64][40];
    unsigned* Bw = (unsigned*)Bs;
    f32x4 acc[4] = {};
    const int kp = t >> 4, n4 = (t & 15) * 4;
    #pragma unroll
    for (int kc = 0; kc < 8; kc++) {
        const ushort4 a0 = *(const ushort4*)(Xb + (size_t)(kc * 32 + 2 * kp) * LL + n0 + n4);
        const ushort4 a1 = *(const ushort4*)(Xb + (size_t)(kc * 32 + 2 * kp + 1) * LL + n0 + n4);
        if (kc) __syncthreads();
        Bw[(n4 + 0) * 20 + kp] = (unsigned)a0.x | ((unsigned)a1.x << 16);
        Bw[(n4 + 1) * 20 + kp] = (unsigned)a0.y | ((unsigned)a1.y << 16);
        Bw[(n4 + 2) * 20 + kp] = (unsigned)a0.z | ((unsigned)a1.z << 16);
        Bw[(n4 + 3) * 20 + kp] = (unsigned)a0.w | ((unsigned)a1.w << 16);
        __syncthreads();
        #pragma unroll
        for (int ns = 0; ns < 4; ns++) {
            const bf16x8 bf = *(const bf16x8*)(&Bs[ns * 16 + nf][qb * 8]);
            acc[ns] = __builtin_amdgcn_mfma_f32_16x16x32_bf16(afrag[kc], bf, acc[ns], 0, 0, 0);
        }
    }
    #pragma unroll
    for (int ns = 0; ns < 4; ns++)
        #pragma unroll
        for (int r = 0; r < 4; r++) {
            const int m = mbase + w * 16 + qb * 4 + r;
            outg[((size_t)zi * CC + m) * LL + n0 + ns * 16 + nf] = acc[ns][r];
        }
}

// ================= Fully fused selective scan (512 thr, CH=8, bf16 streams) ==
// NOTE: __launch_bounds__(512, 8) is load-bearing for correctness-in-practice:
// the (512,4) variant passed first validation but diverged under graph replay
// (r16) — empirically poisoned, do not revisit.  Anti-spill here is via
// unroll-2 on the n-loops (lower transient pressure on the 64-VGPR budget).
__global__ __launch_bounds__(512, 8) void scan_fused(
    const float* __restrict__ xpre, const unsigned short* __restrict__ xdbl16,
    const float* __restrict__ A_log,
    const float* __restrict__ Wdt0, const float* __restrict__ Wdt1,
    const float* __restrict__ bdt0, const float* __restrict__ bdt1,
    const float* __restrict__ cw0, const float* __restrict__ cb0,
    const float* __restrict__ cw1, const float* __restrict__ cb1,
    const float* __restrict__ D0, const float* __restrict__ D1,
    const unsigned short* __restrict__ zb16, unsigned short* __restrict__ yb)
{
    const int blk = blockIdx.x;          // zi*DI + d
    const int zi = blk >> 8;
    const int d  = blk & (DI - 1);
    const int t = threadIdx.x;
    const int l0 = t * CH;
    __shared__ float Ssh[DS * (NCH + 1)];   // stride 513
    __shared__ float sdl_sh[NCH];
    __shared__ float Pseg[DS * (SEG + 1)];  // stride 33
    __shared__ float Sseg[DS * (SEG + 1)];
    const float* x_g = xpre + (size_t)blk * LL;
    const unsigned short* xdb = xdbl16 + (size_t)zi * DX * LL;
    const float* Wdt = (zi >= BB) ? Wdt1 : Wdt0;
    const float* bdt = (zi >= BB) ? bdt1 : bdt0;
    const float dbias = bdt[d];
    const float* cw = (zi >= BB) ? cw1 : cw0;
    const float* cb = (zi >= BB) ? cb1 : cb0;
    const float w0 = cw[d * 4 + 0], w1 = cw[d * 4 + 1];
    const float w2 = cw[d * 4 + 2], w3 = cw[d * 4 + 3];
    const float cbias = cb[d];
    float e[CH], rdlx[CH];
    {
        // ---- x + conv + SiLU (prolog-local rx) ----
        float rx[CH];
        {
            float xv[CH + 3];
            if (t > 0) {
                const float4 hm = *(const float4*)(x_g + l0 - 4);
                xv[0] = hm.y; xv[1] = hm.z; xv[2] = hm.w;
            } else { xv[0] = 0.f; xv[1] = 0.f; xv[2] = 0.f; }
            #pragma unroll
            for (int j = 0; j < 2; j++) {
                const float4 v = *(const float4*)(x_g + l0 + 4 * j);
                xv[4 * j + 3] = v.x; xv[4 * j + 4] = v.y;
                xv[4 * j + 5] = v.z; xv[4 * j + 6] = v.w;
            }
            #pragma unroll
            for (int i = 0; i < CH; i++)
                rx[i] = siluf(w0 * xv[i] + w1 * xv[i + 1] + w2 * xv[i + 2] + w3 * xv[i + 3] + cbias);
        }
        // ---- delta pre-activation from bf16 dt rows ----
        float acc[CH];
        #pragma unroll
        for (int i = 0; i < CH; i++) acc[i] = dbias;
        #pragma unroll
        for (int r = 0; r < DR; r++) {
            const float wr = Wdt[d * DR + r];
            const uint4 v = *(const uint4*)(xdb + (size_t)r * LL + l0);
            acc[0] = fmaf(wr, bflo(v.x), acc[0]); acc[1] = fmaf(wr, bfhi(v.x), acc[1]);
            acc[2] = fmaf(wr, bflo(v.y), acc[2]); acc[3] = fmaf(wr, bfhi(v.y), acc[3]);
            acc[4] = fmaf(wr, bflo(v.z), acc[4]); acc[5] = fmaf(wr, bfhi(v.z), acc[5]);
            acc[6] = fmaf(wr, bflo(v.w), acc[6]); acc[7] = fmaf(wr, bfhi(v.w), acc[7]);
        }
        float sdl = 0.f;
        #pragma unroll
        for (int i = 0; i < CH; i++) {
            const float sp = softplusf(acc[i]);
            sdl += sp;
            rdlx[i] = sp * rx[i];
            e[i] = __expf(-sp);
        }
        sdl_sh[t] = sdl;
    }
    // ---- detect integer-An structure (block-uniform) ----
    bool fast = true;
    #pragma unroll
    for (int n = 0; n < DS; n++)
        fast = fast && (fabsf(__expf(A_log[d * DS + n]) - (float)(n + 1)) < 1e-3f);
    const unsigned short* Bbase = xdb + (size_t)DR * LL;
    const unsigned short* Cbase = Bbase + (size_t)DS * LL;
    float y[CH];
    const int n2 = t & 15, sg = t >> 4;

    if (fast) {
        float pw[CH];
        #pragma unroll
        for (int i = 0; i < CH; i++) pw[i] = 1.f;
        // ---- phase1: local scans (h_in = 0), decay via power chain ----
        #pragma unroll 2
        for (int n = 0; n < DS; n++) {
            const uint4 bv = *(const uint4*)(Bbase + (size_t)n * LL + l0);
            float hn = 0.f;
            pw[0] *= e[0]; hn = fmaf(pw[0], hn, rdlx[0] * bflo(bv.x));
            pw[1] *= e[1]; hn = fmaf(pw[1], hn, rdlx[1] * bfhi(bv.x));
            pw[2] *= e[2]; hn = fmaf(pw[2], hn, rdlx[2] * bflo(bv.y));
            pw[3] *= e[3]; hn = fmaf(pw[3], hn, rdlx[3] * bfhi(bv.y));
            pw[4] *= e[4]; hn = fmaf(pw[4], hn, rdlx[4] * bflo(bv.z));
            pw[5] *= e[5]; hn = fmaf(pw[5], hn, rdlx[5] * bfhi(bv.z));
            pw[6] *= e[6]; hn = fmaf(pw[6], hn, rdlx[6] * bflo(bv.w));
            pw[7] *= e[7]; hn = fmaf(pw[7], hn, rdlx[7] * bfhi(bv.w));
            Ssh[n * (NCH + 1) + t] = hn;
        }
        __syncthreads();
        // ---- phase2a: per-(n2, segment) compose (P,S) ----
        {
            const float Ann = -(float)(n2 + 1);
            float P = 1.f, S = 0.f;
            #pragma unroll
            for (int k = 0; k < 16; k++) {
                const int c = sg * 16 + k;
                const float p = __expf(Ann * sdl_sh[c]);
                const float s = Ssh[n2 * (NCH + 1) + c];
                S = fmaf(p, S, s);
                P *= p;
            }
            Pseg[n2 * (SEG + 1) + sg] = P;
            Sseg[n2 * (SEG + 1) + sg] = S;
        }
        __syncthreads();
        // ---- phase2b: 16 threads scan 32 segments each ----
        if (t < DS) {
            float h = 0.f;
            #pragma unroll 4
            for (int c2 = 0; c2 < SEG; c2++) {
                const float p = Pseg[t * (SEG + 1) + c2];
                const float s = Sseg[t * (SEG + 1) + c2];
                Sseg[t * (SEG + 1) + c2] = h;
                h = fmaf(p, h, s);
            }
        }
        __syncthreads();
        // ---- phase2c: replay within segment -> h_in per chunk ----
        {
            const float Ann = -(float)(n2 + 1);
            float h = Sseg[n2 * (SEG + 1) + sg];
            #pragma unroll
            for (int k = 0; k < 16; k++) {
                const int c = sg * 16 + k;
                const float p = __expf(Ann * sdl_sh[c]);
                const float s = Ssh[n2 * (NCH + 1) + c];
                Ssh[n2 * (NCH + 1) + c] = h;
                h = fmaf(p, h, s);
            }
        }
        __syncthreads();
        // ---- phase3: re-scan from h_in, y = sum_n h*C ----
        #pragma unroll
        for (int i = 0; i < CH; i++) { y[i] = 0.f; pw[i] = 1.f; }
        #pragma unroll 2
        for (int n = 0; n < DS; n++) {
            const uint4 bv = *(const uint4*)(Bbase + (size_t)n * LL + l0);
            const uint4 cv = *(const uint4*)(Cbase + (size_t)n * LL + l0);
            float hn = Ssh[n * (NCH + 1) + t];
            pw[0] *= e[0]; hn = fmaf(pw[0], hn, rdlx[0] * bflo(bv.x)); y[0] = fmaf(hn, bflo(cv.x), y[0]);
            pw[1] *= e[1]; hn = fmaf(pw[1], hn, rdlx[1] * bfhi(bv.x)); y[1] = fmaf(hn, bfhi(cv.x), y[1]);
            pw[2] *= e[2]; hn = fmaf(pw[2], hn, rdlx[2] * bflo(bv.y)); y[2] = fmaf(hn, bflo(cv.y), y[2]);
            pw[3] *= e[3]; hn = fmaf(pw[3], hn, rdlx[3] * bfhi(bv.y)); y[3] = fmaf(hn, bfhi(cv.y), y[3]);
            pw[4] *= e[4]; hn = fmaf(pw[4], hn, rdlx[4] * bflo(bv.z)); y[4] = fmaf(hn, bflo(cv.z), y[4]);
            pw[5] *= e[5]; hn = fmaf(pw[5], hn, rdlx[5] * bfhi(bv.z)); y[5] = fmaf(hn, bfhi(cv.z), y[5]);
            pw[6] *= e[6]; hn = fmaf(pw[6], hn, rdlx[6] * bflo(bv.w)); y[6] = fmaf(hn, bflo(cv.w), y[6]);
            pw[7] *= e[7]; hn = fmaf(pw[7], hn, rdlx[7] * bfhi(bv.w)); y[7] = fmaf(hn, bfhi(cv.w), y[7]);
        }
    } else {
        // ---- generic fallback: rdl recovered as -ln(e) (cold path) ----
        float rdl[CH];
        #pragma unroll
        for (int i = 0; i < CH; i++) rdl[i] = -0.69314718f * log2f(e[i]);
        #pragma unroll 2
        for (int n = 0; n < DS; n++) {
            const float An = -__expf(A_log[d * DS + n]);
            const uint4 bv = *(const uint4*)(Bbase + (size_t)n * LL + l0);
            float hn = 0.f;
            hn = fmaf(__expf(rdl[0] * An), hn, rdlx[0] * bflo(bv.x));
            hn = fmaf(__expf(rdl[1] * An), hn, rdlx[1] * bfhi(bv.x));
            hn = fmaf(__expf(rdl[2] * An), hn, rdlx[2] * bflo(bv.y));
            hn = fmaf(__expf(rdl[3] * An), hn, rdlx[3] * bfhi(bv.y));
            hn = fmaf(__expf(rdl[4] * An), hn, rdlx[4] * bflo(bv.z));
            hn = fmaf(__expf(rdl[5] * An), hn, rdlx[5] * bfhi(bv.z));
            hn = fmaf(__expf(rdl[6] * An), hn, rdlx[6] * bflo(bv.w));
            hn = fmaf(__expf(rdl[7] * An), hn, rdlx[7] * bfhi(bv.w));
            Ssh[n * (NCH + 1) + t] = hn;
        }
        __syncthreads();
        {
            const float Ann = -__expf(A_log[d * DS + n2]);
            float P = 1.f, S = 0.f;
            #pragma unroll
            for (int k = 0; k < 16; k++) {
                const int c = sg * 16 + k;
                const float p = __expf(Ann * sdl_sh[c]);
                const float s = Ssh[n2 * (NCH + 1) + c];
                S = fmaf(p, S, s);
                P *= p;
            }
            Pseg[n2 * (SEG + 1) + sg] = P;
            Sseg[n2 * (SEG + 1) + sg] = S;
        }
        __syncthreads();
        if (t < DS) {
            float h = 0.f;
            #pragma unroll 4
            for (int c2 = 0; c2 < SEG; c2++) {
                const float p = Pseg[t * (SEG + 1) + c2];
                const float s = Sseg[t * (SEG + 1) + c2];
                Sseg[t * (SEG + 1) + c2] = h;
                h = fmaf(p, h, s);
            }
        }
        __syncthreads();
        {
            const float Ann = -__expf(A_log[d * DS + n2]);
            float h = Sseg[n2 * (SEG + 1) + sg];
            #pragma unroll
            for (int k = 0; k < 16; k++) {
                const int c = sg * 16 + k;
                const float p = __expf(Ann * sdl_sh[c]);
                const float s = Ssh[n2 * (NCH + 1) + c];
                Ssh[n2 * (NCH + 1) + c] = h;
                h = fmaf(p, h, s);
            }
        }
        __syncthreads();
        #pragma unroll
        for (int i = 0; i < CH; i++) y[i] = 0.f;
        #pragma unroll 2
        for (int n = 0; n < DS; n++) {
            const float An = -__expf(A_log[d * DS + n]);
            const uint4 bv = *(const uint4*)(Bbase + (size_t)n * LL + l0);
            const uint4 cv = *(const uint4*)(Cbase + (size_t)n * LL + l0);
            float hn = Ssh[n * (NCH + 1) + t];
            hn = fmaf(__expf(rdl[0] * An), hn, rdlx[0] * bflo(bv.x)); y[0] = fmaf(hn, bflo(cv.x), y[0]);
            hn = fmaf(__expf(rdl[1] * An), hn, rdlx[1] * bfhi(bv.x)); y[1] = fmaf(hn, bfhi(cv.x), y[1]);
            hn = fmaf(__expf(rdl[2] * An), hn, rdlx[2] * bflo(bv.y)); y[2] = fmaf(hn, bflo(cv.y), y[2]);
            hn = fmaf(__expf(rdl[3] * An), hn, rdlx[3] * bfhi(bv.y)); y[3] = fmaf(hn, bfhi(cv.y), y[3]);
            hn = fmaf(__expf(rdl[4] * An), hn, rdlx[4] * bflo(bv.z)); y[4] = fmaf(hn, bflo(cv.z), y[4]);
            hn = fmaf(__expf(rdl[5] * An), hn, rdlx[5] * bfhi(bv.z)); y[5] = fmaf(hn, bfhi(cv.z), y[5]);
            hn = fmaf(__expf(rdl[6] * An), hn, rdlx[6] * bflo(bv.w)); y[6] = fmaf(hn, bflo(cv.w), y[6]);
            hn = fmaf(__expf(rdl[7] * An), hn, rdlx[7] * bfhi(bv.w)); y[7] = fmaf(hn, bfhi(cv.w), y[7]);
        }
    }
    // ---- gate: recompute rx from L2-warm x reload; z from bf16 ----
    const float Dd = ((zi >= BB) ? D1 : D0)[d];
    const unsigned short* z_g = zb16 + (size_t)blk * LL + l0;
    unsigned short* y_g = yb + (size_t)blk * LL + l0;
    {
        float xv[CH + 3];
        if (t > 0) {
            const float4 hm = *(const float4*)(x_g + l0 - 4);
            xv[0] = hm.y; xv[1] = hm.z; xv[2] = hm.w;
        } else { xv[0] = 0.f; xv[1] = 0.f; xv[2] = 0.f; }
        #pragma unroll
        for (int j = 0; j < 2; j++) {
            const float4 v = *(const float4*)(x_g + l0 + 4 * j);
            xv[4 * j + 3] = v.x; xv[4 * j + 4] = v.y;
            xv[4 * j + 5] = v.z; xv[4 * j + 6] = v.w;
        }
        const uint4 zv = *(const uint4*)z_g;
        float zf[CH];
        zf[0] = bflo(zv.x); zf[1] = bfhi(zv.x); zf[2] = bflo(zv.y); zf[3] = bfhi(zv.y);
        zf[4] = bflo(zv.z); zf[5] = bfhi(zv.z); zf[6] = bflo(zv.w); zf[7] = bfhi(zv.w);
        ushort4 r0, r1;
        #pragma unroll
        for (int i = 0; i < CH; i++) {
            const float rxi = siluf(w0 * xv[i] + w1 * xv[i + 1] + w2 * xv[i + 2] + w3 * xv[i + 3] + cbias);
            const float val = (y[i] + Dd * rxi) * siluf(zf[i]);
            if (i < 4) ((unsigned short*)&r0)[i] = f2bf(val);
            else       ((unsigned short*)&r1)[i - 4] = f2bf(val);
        }
        *(ushort4*)(y_g + 0) = r0;
        *(ushort4*)(y_g + 4) = r1;
    }
}

extern "C" void kernel_launch(void* const* d_in, const int* in_sizes, int n_in,
                              void* d_out, int out_size, void* d_ws, size_t ws_size,
                              hipStream_t stream)
{
    (void)in_sizes; (void)n_in; (void)out_size; (void)ws_size;
    auto fp = [&](int i) { return (const float*)d_in[i]; };
    const float *pan = fp(0), *ms = fp(1);
    const float *nwp = fp(2), *nbp = fp(3), *nwm = fp(4), *nbm = fp(5);
    const float *Winp = fp(6), *Winm = fp(7), *Wzp = fp(8), *Wzm = fp(9);
    const float *cwp = fp(10), *cbp = fp(11), *cwm = fp(12), *cbm = fp(13);
    const float *Wxp = fp(14), *Wxm = fp(15);
    const float *Wdtp = fp(16), *Wdtm = fp(17), *bdtp = fp(18), *bdtm = fp(19);
    const float *Alog = fp(20), *Dp = fp(21), *Dm = fp(22);
    const float *Woutp = fp(23), *Woutm = fp(24);

    float* ws = (float*)d_ws;
    unsigned short* x3b = (unsigned short*)ws;                 // NZ*CC*LL bf16
    float* xpre = ws + (size_t)NZ * CC * LL / 2;               // NZ*DI*LL f32
    unsigned short* zb16 = (unsigned short*)(xpre + (size_t)NZ * DI * LL);   // NZ*DI*LL bf16
    unsigned short* xdbl16 = zb16 + (size_t)NZ * DI * LL;      // NZ*DX*LL bf16
    unsigned short* yb = xdbl16 + (size_t)NZ * DX * LL;        // NZ*DI*LL bf16
    unsigned short* wb = yb + (size_t)NZ * DI * LL;            // 217088 bf16
    float* out = (float*)d_out;

    convert_w_kernel<<<dim3(848), 256, 0, stream>>>(Winp, Winm, Wzp, Wzm, Woutp, Woutm, Wxp, Wxm, wb);
    layernorm_kernel<<<dim3(LL / 64, NZ), 256, 0, stream>>>(pan, ms, nwp, nbp, nwm, nbm, x3b);
    gemm_inz_mfma<<<dim3(LL / 64, 8, NZ), 256, 0, stream>>>(wb, x3b, xpre, zb16);
    gemm_x_mfma<<<dim3(LL / 64, 1, NZ), 256, 0, stream>>>(wb, xpre, cwp, cbp, cwm, cbm, xdbl16);
    scan_fused<<<dim3(NZ * DI), 512, 0, stream>>>(xpre, xdbl16, Alog, Wdtp, Wdtm, bdtp, bdtm,
                                                  cwp, cbp, cwm, cbm, Dp, Dm, zb16, yb);
    gemm_out_mfma<<<dim3(LL / 64, 2, NZ), 256, 0, stream>>>(wb, yb, out);
}